// Round 7
// baseline (92.783 us; speedup 1.0000x reference)
//
#include <hip/hip_runtime.h>
#include <hip/hip_bf16.h>
#include <math.h>

#define HID   128
#define TPB   256      // 4 waves per block, 16 rows per wave -> 64 rows per block-tile
#define TROWS 64
#define NBLK  512      // persistent grid

typedef __attribute__((ext_vector_type(8))) short        short8v;   // 8 bf16
typedef __attribute__((ext_vector_type(4))) float        f32x4;
typedef __attribute__((ext_vector_type(4))) unsigned int uint4v;

#define MFMA(a, b, c) __builtin_amdgcn_mfma_f32_16x16x32_bf16((a), (b), (c), 0, 0, 0)
#define SCHED_FENCE() __builtin_amdgcn_sched_barrier(0)

__device__ __forceinline__ unsigned int pk2bf(float lo, float hi) {
    unsigned short a = __builtin_bit_cast(unsigned short, __float2bfloat16(lo));
    unsigned short b = __builtin_bit_cast(unsigned short, __float2bfloat16(hi));
    return (unsigned int)a | ((unsigned int)b << 16);
}
__device__ __forceinline__ f32x4 relu4(f32x4 v) {
    f32x4 r;
    r.x = fmaxf(v.x, 0.f); r.y = fmaxf(v.y, 0.f);
    r.z = fmaxf(v.z, 0.f); r.w = fmaxf(v.w, 0.f);
    return r;
}

// min-waves/EU = 1 -> 512-reg unified budget: room for ~176 persistent
// operand registers (W2/W3/b2 fragments) + transients, zero scratch.
__global__ __launch_bounds__(TPB, 1)
void stress_kernel(const float* __restrict__ F,
                   const float* __restrict__ W1, const float* __restrict__ b1,
                   const float* __restrict__ W2, const float* __restrict__ b2,
                   const float* __restrict__ W3, const float* __restrict__ b3,
                   float* __restrict__ out, int N)
{
    // ---- LDS: staging + per-tile broadcast weights (38.5 KB) ----
    __shared__ uint4v sA2[2048];   // W2^T A-frags: [(jt*4+ks)*64 + lane]
    __shared__ uint4v sA3[256];    // W3^T A-frags: [ks2*64 + lane]
    __shared__ __align__(16) float sW1[3 * HID];
    __shared__ __align__(16) float sb1[HID];
    __shared__ __align__(16) float sb2[HID];

    const int tid  = threadIdx.x;
    const int lane = tid & 63;
    const int wid  = tid >> 6;
    const int g    = lane >> 4;     // lane group 0..3
    const int lr   = lane & 15;

    // ---- one-time per-block weight staging / swizzling ----
    for (int e = tid; e < 2048; e += TPB) {
        int l = e & 63, ks = (e >> 6) & 3, jt = e >> 8;
        int k0 = 8 * (l >> 4) + 32 * ks;
        int j  = (l & 15) + 16 * jt;
        uint4v v;
        v.x = pk2bf(W2[(k0 + 0) * HID + j], W2[(k0 + 1) * HID + j]);
        v.y = pk2bf(W2[(k0 + 2) * HID + j], W2[(k0 + 3) * HID + j]);
        v.z = pk2bf(W2[(k0 + 4) * HID + j], W2[(k0 + 5) * HID + j]);
        v.w = pk2bf(W2[(k0 + 6) * HID + j], W2[(k0 + 7) * HID + j]);
        sA2[e] = v;
    }
    for (int e = tid; e < 256; e += TPB) {
        int l = e & 63, ks2 = e >> 6;
        int gg = l >> 4, t = l & 15;
        float w0  = (t < 4) ? W3[(4 * gg + 0 + 16 * (2 * ks2 + 0)) * 4 + t] : 0.f;
        float w1_ = (t < 4) ? W3[(4 * gg + 1 + 16 * (2 * ks2 + 0)) * 4 + t] : 0.f;
        float w2_ = (t < 4) ? W3[(4 * gg + 2 + 16 * (2 * ks2 + 0)) * 4 + t] : 0.f;
        float w3_ = (t < 4) ? W3[(4 * gg + 3 + 16 * (2 * ks2 + 0)) * 4 + t] : 0.f;
        float w4  = (t < 4) ? W3[(4 * gg + 0 + 16 * (2 * ks2 + 1)) * 4 + t] : 0.f;
        float w5  = (t < 4) ? W3[(4 * gg + 1 + 16 * (2 * ks2 + 1)) * 4 + t] : 0.f;
        float w6  = (t < 4) ? W3[(4 * gg + 2 + 16 * (2 * ks2 + 1)) * 4 + t] : 0.f;
        float w7  = (t < 4) ? W3[(4 * gg + 3 + 16 * (2 * ks2 + 1)) * 4 + t] : 0.f;
        uint4v v;
        v.x = pk2bf(w0, w1_); v.y = pk2bf(w2_, w3_);
        v.z = pk2bf(w4, w5);  v.w = pk2bf(w6, w7);
        sA3[e] = v;
    }
    for (int i = tid; i < 3 * HID; i += TPB) sW1[i] = W1[i];
    for (int i = tid; i < HID; i += TPB)     { sb1[i] = b1[i]; sb2[i] = b2[i]; }
    __syncthreads();

    // typed LDS vector views (per-tile broadcast reads)
    const f32x4* pW1 = (const f32x4*)sW1;
    const f32x4* pB1 = (const f32x4*)sb1;
    const f32x4* pB2 = (const f32x4*)sb2;

    // ---- hoist ALL loop-invariant operand fragments into registers ----
    #define A2DECL(JT) \
        const short8v a2_##JT##_0 = __builtin_bit_cast(short8v, sA2[((JT)*4+0)*64+lane]), \
                      a2_##JT##_1 = __builtin_bit_cast(short8v, sA2[((JT)*4+1)*64+lane]), \
                      a2_##JT##_2 = __builtin_bit_cast(short8v, sA2[((JT)*4+2)*64+lane]), \
                      a2_##JT##_3 = __builtin_bit_cast(short8v, sA2[((JT)*4+3)*64+lane]);
    A2DECL(0) A2DECL(1) A2DECL(2) A2DECL(3)
    A2DECL(4) A2DECL(5) A2DECL(6) A2DECL(7)
    #undef A2DECL
    const short8v a3f_0 = __builtin_bit_cast(short8v, sA3[0 * 64 + lane]);
    const short8v a3f_1 = __builtin_bit_cast(short8v, sA3[1 * 64 + lane]);
    const short8v a3f_2 = __builtin_bit_cast(short8v, sA3[2 * 64 + lane]);
    const short8v a3f_3 = __builtin_bit_cast(short8v, sA3[3 * 64 + lane]);
    const f32x4 ba_0 = pB2[g + 0], bb_0 = pB2[g + 4];
    const f32x4 ba_1 = pB2[g + 8], bb_1 = pB2[g + 12];
    const f32x4 ba_2 = pB2[g + 16], bb_2 = pB2[g + 20];
    const f32x4 ba_3 = pB2[g + 24], bb_3 = pB2[g + 28];

    const int nTiles = (N + TROWS - 1) / TROWS;
    const int tile0  = blockIdx.x;

    // prefetch F for the first tile
    f32x4 fv = {0.f, 0.f, 0.f, 0.f};
    {
        const int n = tile0 * TROWS + wid * 16 + lr;
        if (lane < 16 && tile0 < nTiles && n < N) fv = ((const f32x4*)F)[n];
    }

    for (int tile = tile0; tile < nTiles; tile += gridDim.x) {
        const int n = tile * TROWS + wid * 16 + lr;

        // ---- prologue: invariants + polar R from prefetched fv ----
        float fa = fv.x, fb = fv.y, fc = fv.z, fd = fv.w;
        float x0 = 0.f, x1 = 0.f, x2 = 0.f;
        float R00 = 0.f, R01 = 0.f, R10 = 0.f, R11 = 0.f;
        {
            const float J   = fa * fd - fb * fc;
            const float ss  = fa * fa + fb * fb + fc * fc + fd * fd;
            const float sgn = (J >= 0.f) ? 1.f : -1.f;
            const float r   = sqrtf(fmaxf(ss + 2.f * fabsf(J), 1e-30f));
            const float inv = 1.f / r;
            x0 = r - 2.f; x1 = ss - 1.f; x2 = J - 1.f;
            R00 = (fa + sgn * fd) * inv; R01 = (fb - sgn * fc) * inv;
            R10 = (fc - sgn * fb) * inv; R11 = (fd + sgn * fa) * inv;
        }
        const float xa0 = __shfl(x0, lr, 64);
        const float xa1 = __shfl(x1, lr, 64);
        const float xa2 = __shfl(x2, lr, 64);
        SCHED_FENCE();

        // prefetch next tile's F (hides HBM latency under compute)
        {
            const int tn = tile + gridDim.x;
            const int nn = tn * TROWS + wid * 16 + lr;
            fv = (f32x4){0.f, 0.f, 0.f, 0.f};
            if (lane < 16 && tn < nTiles && nn < N) fv = ((const f32x4*)F)[nn];
        }
        SCHED_FENCE();

        // ---- B-fragment build (h1 on the fly; W1/b1 broadcast LDS reads) ----
        short8v bfr_0, bfr_1, bfr_2, bfr_3;
        #define HCOMP(KS, DST) {                                                  \
            const int q = 2 * g + 8 * (KS);                                       \
            const f32x4 w0lo = pW1[q],      w0hi = pW1[q + 1];                    \
            const f32x4 w1lo = pW1[32 + q], w1hi = pW1[32 + q + 1];               \
            const f32x4 w2lo = pW1[64 + q], w2hi = pW1[64 + q + 1];               \
            const f32x4 blo  = pB1[q],      bhi  = pB1[q + 1];                    \
            const f32x4 hlo = relu4(blo + w0lo * xa0 + w1lo * xa1 + w2lo * xa2);  \
            const f32x4 hhi = relu4(bhi + w0hi * xa0 + w1hi * xa1 + w2hi * xa2);  \
            uint4v u;                                                             \
            u.x = pk2bf(hlo.x, hlo.y); u.y = pk2bf(hlo.z, hlo.w);                 \
            u.z = pk2bf(hhi.x, hhi.y); u.w = pk2bf(hhi.z, hhi.w);                 \
            DST = __builtin_bit_cast(short8v, u);                                 \
        } SCHED_FENCE();

        f32x4 acc_0 = {0.f,0.f,0.f,0.f}, acc_1 = {0.f,0.f,0.f,0.f},
              acc_2 = {0.f,0.f,0.f,0.f}, acc_3 = {0.f,0.f,0.f,0.f},
              acc_4 = {0.f,0.f,0.f,0.f}, acc_5 = {0.f,0.f,0.f,0.f},
              acc_6 = {0.f,0.f,0.f,0.f}, acc_7 = {0.f,0.f,0.f,0.f};

        #define STEP(JT, KS, BF) acc_##JT = MFMA(a2_##JT##_##KS, BF, acc_##JT)
        #define KSGROUP(KS, BF) {                                                 \
            STEP(0, KS, BF); STEP(1, KS, BF); STEP(2, KS, BF); STEP(3, KS, BF);   \
            STEP(4, KS, BF); STEP(5, KS, BF); STEP(6, KS, BF); STEP(7, KS, BF);   \
        } SCHED_FENCE();

        // software pipeline: h-compute (VALU) overlaps MFMA execution
        HCOMP(0, bfr_0)
        HCOMP(1, bfr_1)
        KSGROUP(0, bfr_0)
        HCOMP(2, bfr_2)
        KSGROUP(1, bfr_1)
        HCOMP(3, bfr_3)
        KSGROUP(2, bfr_2)
        KSGROUP(3, bfr_3)
        #undef KSGROUP
        #undef STEP
        #undef HCOMP

        // ---- layer 3: y^T = W3^T * relu(h2 + b2) ----
        f32x4 accY = {0.f, 0.f, 0.f, 0.f};
        #define L3(KS2, A, B) {                                                   \
            const f32x4 ha = relu4((A) + ba_##KS2);                               \
            const f32x4 hb = relu4((B) + bb_##KS2);                               \
            uint4v u;                                                             \
            u.x = pk2bf(ha.x, ha.y); u.y = pk2bf(ha.z, ha.w);                     \
            u.z = pk2bf(hb.x, hb.y); u.w = pk2bf(hb.z, hb.w);                     \
            accY = MFMA(a3f_##KS2, __builtin_bit_cast(short8v, u), accY);         \
        } SCHED_FENCE();
        L3(0, acc_0, acc_1) L3(1, acc_2, acc_3)
        L3(2, acc_4, acc_5) L3(3, acc_6, acc_7)
        #undef L3

        // ---- epilogue: lanes 0..15 hold y[0..3] of row n ----
        if (lane < 16 && n < N) {
            const float y0 = accY.x, y1 = accY.y, y2 = accY.z, y3 = accY.w;
            const float s01 = 0.5f * (y1 + y2);
            const float P00 = R00 * y0  + R01 * s01;
            const float P01 = R00 * s01 + R01 * y3;
            const float P10 = R10 * y0  + R11 * s01;
            const float P11 = R10 * s01 + R11 * y3;
            f32x4 o;
            o.x = P00 * fa + P01 * fb;   // cauchy = P @ F^T
            o.y = P00 * fc + P01 * fd;
            o.z = P10 * fa + P11 * fb;
            o.w = P10 * fc + P11 * fd;
            ((f32x4*)out)[n] = o;
        }
        SCHED_FENCE();
    }
}

extern "C" void kernel_launch(void* const* d_in, const int* in_sizes, int n_in,
                              void* d_out, int out_size, void* d_ws, size_t ws_size,
                              hipStream_t stream) {
    const float* F  = (const float*)d_in[0];
    const float* W1 = (const float*)d_in[1];
    const float* b1 = (const float*)d_in[2];
    const float* W2 = (const float*)d_in[3];
    const float* b2 = (const float*)d_in[4];
    const float* W3 = (const float*)d_in[5];
    const float* b3 = (const float*)d_in[6];
    float* out = (float*)d_out;
    const int N = in_sizes[0] / 4;

    const int nTiles = (N + TROWS - 1) / TROWS;
    int grid = nTiles < NBLK ? nTiles : NBLK;
    stress_kernel<<<dim3(grid), dim3(TPB), 0, stream>>>(F, W1, b1, W2, b2, W3, b3, out, N);
}

// Round 8
// 64.538 us; speedup vs baseline: 1.4376x; 1.4376x over previous
//
#include <hip/hip_runtime.h>
#include <hip/hip_bf16.h>
#include <math.h>

#define HID   128
#define TPB   256      // 4 waves per block, 64 rows per wave -> 256 rows per block-tile
#define TROWS 256
#define NBLK  512      // persistent grid (2 blocks/CU)

typedef __attribute__((ext_vector_type(8))) short        short8v;   // 8 bf16
typedef __attribute__((ext_vector_type(4))) float        f32x4;
typedef __attribute__((ext_vector_type(4))) unsigned int uint4v;

#define MFMA(a, b, c) __builtin_amdgcn_mfma_f32_16x16x32_bf16((a), (b), (c), 0, 0, 0)
#define SCHED_FENCE() __builtin_amdgcn_sched_barrier(0)

__device__ __forceinline__ unsigned int pk2bf(float lo, float hi) {
    unsigned short a = __builtin_bit_cast(unsigned short, __float2bfloat16(lo));
    unsigned short b = __builtin_bit_cast(unsigned short, __float2bfloat16(hi));
    return (unsigned int)a | ((unsigned int)b << 16);
}
__device__ __forceinline__ f32x4 relu4(f32x4 v) {
    f32x4 r;
    r.x = fmaxf(v.x, 0.f); r.y = fmaxf(v.y, 0.f);
    r.z = fmaxf(v.z, 0.f); r.w = fmaxf(v.w, 0.f);
    return r;
}

// 2 waves/EU -> 256-reg unified budget: 128 AGPR (layer-2 acc) + ~95 VGPR peak.
__global__ __launch_bounds__(TPB, 2)
void stress_kernel(const float* __restrict__ F,
                   const float* __restrict__ W1, const float* __restrict__ b1,
                   const float* __restrict__ W2, const float* __restrict__ b2,
                   const float* __restrict__ W3, const float* __restrict__ b3,
                   float* __restrict__ out, int N)
{
    // ---- LDS (38.5 KB -> 2 blocks/CU fits easily) ----
    __shared__ uint4v sA2[2048];   // W2^T A-frags: [(jt*4+ks)*64 + lane]
    __shared__ uint4v sA3[256];    // W3^T A-frags: [ks2*64 + lane]
    __shared__ __align__(16) float sW1[3 * HID];
    __shared__ __align__(16) float sb1[HID];
    __shared__ __align__(16) float sb2[HID];

    const int tid  = threadIdx.x;
    const int lane = tid & 63;
    const int wid  = tid >> 6;
    const int g    = lane >> 4;     // lane group 0..3
    const int lr   = lane & 15;

    // ---- one-time per-block weight staging / swizzling ----
    for (int e = tid; e < 2048; e += TPB) {
        int l = e & 63, ks = (e >> 6) & 3, jt = e >> 8;
        int k0 = 8 * (l >> 4) + 32 * ks;
        int j  = (l & 15) + 16 * jt;
        uint4v v;
        v.x = pk2bf(W2[(k0 + 0) * HID + j], W2[(k0 + 1) * HID + j]);
        v.y = pk2bf(W2[(k0 + 2) * HID + j], W2[(k0 + 3) * HID + j]);
        v.z = pk2bf(W2[(k0 + 4) * HID + j], W2[(k0 + 5) * HID + j]);
        v.w = pk2bf(W2[(k0 + 6) * HID + j], W2[(k0 + 7) * HID + j]);
        sA2[e] = v;
    }
    for (int e = tid; e < 256; e += TPB) {
        int l = e & 63, ks2 = e >> 6;
        int gg = l >> 4, t = l & 15;
        float w0  = (t < 4) ? W3[(4 * gg + 0 + 16 * (2 * ks2 + 0)) * 4 + t] : 0.f;
        float w1_ = (t < 4) ? W3[(4 * gg + 1 + 16 * (2 * ks2 + 0)) * 4 + t] : 0.f;
        float w2_ = (t < 4) ? W3[(4 * gg + 2 + 16 * (2 * ks2 + 0)) * 4 + t] : 0.f;
        float w3_ = (t < 4) ? W3[(4 * gg + 3 + 16 * (2 * ks2 + 0)) * 4 + t] : 0.f;
        float w4  = (t < 4) ? W3[(4 * gg + 0 + 16 * (2 * ks2 + 1)) * 4 + t] : 0.f;
        float w5  = (t < 4) ? W3[(4 * gg + 1 + 16 * (2 * ks2 + 1)) * 4 + t] : 0.f;
        float w6  = (t < 4) ? W3[(4 * gg + 2 + 16 * (2 * ks2 + 1)) * 4 + t] : 0.f;
        float w7  = (t < 4) ? W3[(4 * gg + 3 + 16 * (2 * ks2 + 1)) * 4 + t] : 0.f;
        uint4v v;
        v.x = pk2bf(w0, w1_); v.y = pk2bf(w2_, w3_);
        v.z = pk2bf(w4, w5);  v.w = pk2bf(w6, w7);
        sA3[e] = v;
    }
    for (int i = tid; i < 3 * HID; i += TPB) sW1[i] = W1[i];
    for (int i = tid; i < HID; i += TPB)     { sb1[i] = b1[i]; sb2[i] = b2[i]; }
    __syncthreads();

    const f32x4* pW1 = (const f32x4*)sW1;
    const f32x4* pB1 = (const f32x4*)sb1;
    const f32x4* pB2 = (const f32x4*)sb2;

    // small persistent hoists (W3 frags: 16 VGPR)
    const short8v a3f_0 = __builtin_bit_cast(short8v, sA3[0 * 64 + lane]);
    const short8v a3f_1 = __builtin_bit_cast(short8v, sA3[1 * 64 + lane]);
    const short8v a3f_2 = __builtin_bit_cast(short8v, sA3[2 * 64 + lane]);
    const short8v a3f_3 = __builtin_bit_cast(short8v, sA3[3 * 64 + lane]);

    const int nTiles = (N + TROWS - 1) / TROWS;
    const int tile0  = blockIdx.x;

    // prefetch F for the first tile (each lane owns one row)
    f32x4 fv = {0.f, 0.f, 0.f, 0.f};
    {
        const int n = tile0 * TROWS + wid * 64 + lane;
        if (tile0 < nTiles && n < N) fv = ((const f32x4*)F)[n];
    }

    for (int tile = tile0; tile < nTiles; tile += gridDim.x) {
        const int nbase = tile * TROWS + wid * 64;

        // ---- prologue (all 64 lanes): invariants + polar R for own row ----
        const float fa = fv.x, fb = fv.y, fc = fv.z, fd = fv.w;
        float x0, x1, x2, R00, R01, R10, R11;
        {
            const float J   = fa * fd - fb * fc;
            const float ss  = fa * fa + fb * fb + fc * fc + fd * fd;
            const float sgn = (J >= 0.f) ? 1.f : -1.f;
            const float r   = sqrtf(fmaxf(ss + 2.f * fabsf(J), 1e-30f));
            const float inv = 1.f / r;
            x0 = r - 2.f; x1 = ss - 1.f; x2 = J - 1.f;
            R00 = (fa + sgn * fd) * inv; R01 = (fb - sgn * fc) * inv;
            R10 = (fc - sgn * fb) * inv; R11 = (fd + sgn * fa) * inv;
        }
        // broadcast x per row-tile: x_RT_i = x_i of row RT*16+lr
        const float x_0_0 = __shfl(x0,      lr, 64), x_0_1 = __shfl(x1,      lr, 64), x_0_2 = __shfl(x2,      lr, 64);
        const float x_1_0 = __shfl(x0, 16 + lr, 64), x_1_1 = __shfl(x1, 16 + lr, 64), x_1_2 = __shfl(x2, 16 + lr, 64);
        const float x_2_0 = __shfl(x0, 32 + lr, 64), x_2_1 = __shfl(x1, 32 + lr, 64), x_2_2 = __shfl(x2, 32 + lr, 64);
        const float x_3_0 = __shfl(x0, 48 + lr, 64), x_3_1 = __shfl(x1, 48 + lr, 64), x_3_2 = __shfl(x2, 48 + lr, 64);
        SCHED_FENCE();

        // prefetch next tile's F (hides HBM latency under compute)
        {
            const int tn = tile + gridDim.x;
            const int nn = tn * TROWS + wid * 64 + lane;
            fv = (f32x4){0.f, 0.f, 0.f, 0.f};
            if (tn < nTiles && nn < N) fv = ((const f32x4*)F)[nn];
        }
        SCHED_FENCE();

        // ---- layer-2 accumulators: 8 jt x 4 rt (128 regs, AGPR half) ----
        #define ACCDECL(JT) f32x4 acc_##JT##_0 = {0.f,0.f,0.f,0.f}, acc_##JT##_1 = {0.f,0.f,0.f,0.f}, \
                                  acc_##JT##_2 = {0.f,0.f,0.f,0.f}, acc_##JT##_3 = {0.f,0.f,0.f,0.f};
        ACCDECL(0) ACCDECL(1) ACCDECL(2) ACCDECL(3)
        ACCDECL(4) ACCDECL(5) ACCDECL(6) ACCDECL(7)
        #undef ACCDECL

        short8v bfr_0, bfr_1, bfr_2, bfr_3;

        // HB: build B-frag for row-tile RT at k-chunk ks (uses shared W1 regs)
        #define HB(RT) {                                                              \
            const f32x4 hlo = relu4(blo + w0lo * x_##RT##_0 + w1lo * x_##RT##_1 + w2lo * x_##RT##_2); \
            const f32x4 hhi = relu4(bhi + w0hi * x_##RT##_0 + w1hi * x_##RT##_1 + w2hi * x_##RT##_2); \
            uint4v u;                                                                 \
            u.x = pk2bf(hlo.x, hlo.y); u.y = pk2bf(hlo.z, hlo.w);                     \
            u.z = pk2bf(hhi.x, hhi.y); u.w = pk2bf(hhi.z, hhi.w);                     \
            bfr_##RT = __builtin_bit_cast(short8v, u);                                \
        }
        #define HCOMP(KS) {                                                           \
            const int q = 2 * g + 8 * (KS);                                           \
            const f32x4 w0lo = pW1[q],      w0hi = pW1[q + 1];                        \
            const f32x4 w1lo = pW1[32 + q], w1hi = pW1[32 + q + 1];                   \
            const f32x4 w2lo = pW1[64 + q], w2hi = pW1[64 + q + 1];                   \
            const f32x4 blo  = pB1[q],      bhi  = pB1[q + 1];                        \
            HB(0) HB(1) HB(2) HB(3)                                                   \
        } SCHED_FENCE();

        #define STEP(JT, RT) acc_##JT##_##RT = MFMA(af_##JT, bfr_##RT, acc_##JT##_##RT)
        #define KS32(KS) {                                                            \
            const short8v af_0 = __builtin_bit_cast(short8v, sA2[(0*4+(KS))*64+lane]);\
            const short8v af_1 = __builtin_bit_cast(short8v, sA2[(1*4+(KS))*64+lane]);\
            const short8v af_2 = __builtin_bit_cast(short8v, sA2[(2*4+(KS))*64+lane]);\
            const short8v af_3 = __builtin_bit_cast(short8v, sA2[(3*4+(KS))*64+lane]);\
            const short8v af_4 = __builtin_bit_cast(short8v, sA2[(4*4+(KS))*64+lane]);\
            const short8v af_5 = __builtin_bit_cast(short8v, sA2[(5*4+(KS))*64+lane]);\
            const short8v af_6 = __builtin_bit_cast(short8v, sA2[(6*4+(KS))*64+lane]);\
            const short8v af_7 = __builtin_bit_cast(short8v, sA2[(7*4+(KS))*64+lane]);\
            STEP(0,0); STEP(0,1); STEP(0,2); STEP(0,3);                               \
            STEP(1,0); STEP(1,1); STEP(1,2); STEP(1,3);                               \
            STEP(2,0); STEP(2,1); STEP(2,2); STEP(2,3);                               \
            STEP(3,0); STEP(3,1); STEP(3,2); STEP(3,3);                               \
            STEP(4,0); STEP(4,1); STEP(4,2); STEP(4,3);                               \
            STEP(5,0); STEP(5,1); STEP(5,2); STEP(5,3);                               \
            STEP(6,0); STEP(6,1); STEP(6,2); STEP(6,3);                               \
            STEP(7,0); STEP(7,1); STEP(7,2); STEP(7,3);                               \
        } SCHED_FENCE();

        HCOMP(0) KS32(0)
        HCOMP(1) KS32(1)
        HCOMP(2) KS32(2)
        HCOMP(3) KS32(3)
        #undef KS32
        #undef STEP
        #undef HCOMP
        #undef HB

        // ---- layer 3: y^T = W3^T * relu(h2 + b2), 4 accY chains ----
        f32x4 accY_0 = {0.f,0.f,0.f,0.f}, accY_1 = {0.f,0.f,0.f,0.f},
              accY_2 = {0.f,0.f,0.f,0.f}, accY_3 = {0.f,0.f,0.f,0.f};
        #define L3R(RT, JA, JB, KS2) {                                                \
            const f32x4 ha = relu4(acc_##JA##_##RT + ba);                             \
            const f32x4 hb = relu4(acc_##JB##_##RT + bb);                             \
            uint4v u;                                                                 \
            u.x = pk2bf(ha.x, ha.y); u.y = pk2bf(ha.z, ha.w);                         \
            u.z = pk2bf(hb.x, hb.y); u.w = pk2bf(hb.z, hb.w);                         \
            accY_##RT = MFMA(a3f_##KS2, __builtin_bit_cast(short8v, u), accY_##RT);   \
        }
        #define L3K(KS2, JA, JB) {                                                    \
            const f32x4 ba = pB2[g + 8 * (KS2)];                                      \
            const f32x4 bb = pB2[g + 8 * (KS2) + 4];                                  \
            L3R(0, JA, JB, KS2) L3R(1, JA, JB, KS2)                                   \
            L3R(2, JA, JB, KS2) L3R(3, JA, JB, KS2)                                   \
        } SCHED_FENCE();
        L3K(0, 0, 1) L3K(1, 2, 3) L3K(2, 4, 5) L3K(3, 6, 7)
        #undef L3K
        #undef L3R

        // ---- epilogue per row-tile: shfl F/R from owner lane, lanes 0..15 store ----
        #define EPI(RT, ACC) {                                                        \
            const float Ea  = __shfl(fa,  (RT)*16 + lr, 64);                          \
            const float Eb  = __shfl(fb,  (RT)*16 + lr, 64);                          \
            const float Ec  = __shfl(fc,  (RT)*16 + lr, 64);                          \
            const float Ed  = __shfl(fd,  (RT)*16 + lr, 64);                          \
            const float E00 = __shfl(R00, (RT)*16 + lr, 64);                          \
            const float E01 = __shfl(R01, (RT)*16 + lr, 64);                          \
            const float E10 = __shfl(R10, (RT)*16 + lr, 64);                          \
            const float E11 = __shfl(R11, (RT)*16 + lr, 64);                          \
            const int nn = nbase + (RT)*16 + lr;                                      \
            if (lane < 16 && nn < N) {                                                \
                const float y0 = ACC.x, y1 = ACC.y, y2 = ACC.z, y3 = ACC.w;           \
                const float s01 = 0.5f * (y1 + y2);                                   \
                const float P00 = E00 * y0  + E01 * s01;                              \
                const float P01 = E00 * s01 + E01 * y3;                               \
                const float P10 = E10 * y0  + E11 * s01;                              \
                const float P11 = E10 * s01 + E11 * y3;                               \
                f32x4 o;                                                              \
                o.x = P00 * Ea + P01 * Eb;                                            \
                o.y = P00 * Ec + P01 * Ed;                                            \
                o.z = P10 * Ea + P11 * Eb;                                            \
                o.w = P10 * Ec + P11 * Ed;                                            \
                ((f32x4*)out)[nn] = o;                                                \
            }                                                                         \
        }
        EPI(0, accY_0) EPI(1, accY_1) EPI(2, accY_2) EPI(3, accY_3)
        #undef EPI
        SCHED_FENCE();
    }
}

extern "C" void kernel_launch(void* const* d_in, const int* in_sizes, int n_in,
                              void* d_out, int out_size, void* d_ws, size_t ws_size,
                              hipStream_t stream) {
    const float* F  = (const float*)d_in[0];
    const float* W1 = (const float*)d_in[1];
    const float* b1 = (const float*)d_in[2];
    const float* W2 = (const float*)d_in[3];
    const float* b2 = (const float*)d_in[4];
    const float* W3 = (const float*)d_in[5];
    const float* b3 = (const float*)d_in[6];
    float* out = (float*)d_out;
    const int N = in_sizes[0] / 4;

    const int nTiles = (N + TROWS - 1) / TROWS;
    int grid = nTiles < NBLK ? nTiles : NBLK;
    stress_kernel<<<dim3(grid), dim3(TPB), 0, stream>>>(F, W1, b1, W2, b2, W3, b3, out, N);
}